// Round 5
// baseline (325.109 us; speedup 1.0000x reference)
//
#include <hip/hip_runtime.h>
#include <cstdint>
#include <cstddef>

#define B_ 8
#define T_ 4096
#define C_ 256
#define NC_ 128
#define L_ (T_ / NC_)   // 32 steps per chunk
#define M_ (B_ * T_)    // 32768 rows

typedef float f32x4 __attribute__((ext_vector_type(4)));
typedef short bf16x8 __attribute__((ext_vector_type(8)));

__device__ __forceinline__ unsigned short f2b(float f) {
    unsigned int u = __float_as_uint(f);
    u += 0x7fffu + ((u >> 16) & 1u);   // round-to-nearest-even
    return (unsigned short)(u >> 16);
}
__device__ __forceinline__ float b2f(unsigned short h) {
    return __uint_as_float(((unsigned int)h) << 16);
}

// ---------------- fused f32->bf16 convert: x (4096 blocks) + 4 weights --------
// Each block converts 2048 elems. Weights are 65536 elems = 32 blocks each.
__global__ __launch_bounds__(256) void cvt_all(const float* __restrict__ x,
                                               const float* __restrict__ Wk,
                                               const float* __restrict__ Wv,
                                               const float* __restrict__ Wr,
                                               const float* __restrict__ Wo,
                                               unsigned short* __restrict__ xb,
                                               unsigned short* __restrict__ wb) {
    const int bid = blockIdx.x;
    const float* src;
    unsigned short* dst;
    size_t base;
    if (bid < 4096) {
        src = x; dst = xb;
        base = (size_t)bid * 2048;
    } else {
        const int r = bid - 4096;          // 0..127
        const int mat = r >> 5;            // 0..3
        src = (mat == 0) ? Wk : (mat == 1) ? Wv : (mat == 2) ? Wr : Wo;
        dst = wb + (size_t)mat * 65536;
        base = (size_t)(r & 31) * 2048;
    }
    const size_t i = base + (size_t)threadIdx.x * 8;
    float4 a = *(const float4*)(src + i);
    float4 b = *(const float4*)(src + i + 4);
    bf16x8 o;
    o[0] = (short)f2b(a.x); o[1] = (short)f2b(a.y);
    o[2] = (short)f2b(a.z); o[3] = (short)f2b(a.w);
    o[4] = (short)f2b(b.x); o[5] = (short)f2b(b.y);
    o[6] = (short)f2b(b.z); o[7] = (short)f2b(b.w);
    *(bf16x8*)(dst + i) = o;
}

// ---------------- Tiled GEMM: O[m,n] = sum_k A[m,k] * W[n,k] ------------------
// Wave: 16*MT rows x 128 cols. Block: 4 waves = 64*MT rows x 128 cols.
// grid = (M/(64*MT), 2 col-halves, n_mats). mat 0 -> f0 (f32), mat 1 -> f1
// (f32), mat 2 -> b2 (sigmoid, bf16).
// Epilogue: per-wave LDS stage (16 x 132 f32, 2-way banks = free) then
// row-major dwordx4 global stores (2 rows x 512 B contiguous per wave-instr)
// -- fixes the ~1.6 TB/s scattered-dword write ceiling seen in R2/R3.
template <int MT>
__global__ __launch_bounds__(256) void gemm_tile(const unsigned short* __restrict__ A,
                                                 const unsigned short* __restrict__ w0,
                                                 const unsigned short* __restrict__ w1,
                                                 const unsigned short* __restrict__ w2,
                                                 float* __restrict__ f0,
                                                 float* __restrict__ f1,
                                                 unsigned short* __restrict__ b2) {
    __shared__ float stage[4][16 * 132];
    const int wave = threadIdx.x >> 6, lane = threadIdx.x & 63;
    const int quad = lane >> 4, l16 = lane & 15;
    const int m0 = blockIdx.x * (64 * MT) + wave * (16 * MT);
    const int n0 = blockIdx.y * 128;
    const int mat = blockIdx.z;
    const unsigned short* W = (mat == 0) ? w0 : (mat == 1) ? w1 : w2;
    float* myst = stage[wave];

    bf16x8 af[MT][8];
#pragma unroll
    for (int mt = 0; mt < MT; ++mt) {
        const unsigned short* Ar = A + (size_t)(m0 + mt * 16 + l16) * C_ + quad * 8;
#pragma unroll
        for (int kc = 0; kc < 8; ++kc) af[mt][kc] = *(const bf16x8*)(Ar + kc * 32);
    }

#pragma unroll
    for (int mt = 0; mt < MT; ++mt) {
        f32x4 acc[8];
#pragma unroll
        for (int nt = 0; nt < 8; ++nt) acc[nt] = (f32x4){0.f, 0.f, 0.f, 0.f};
#pragma unroll
        for (int nt = 0; nt < 8; ++nt) {
            const unsigned short* Wrow = W + (size_t)(n0 + nt * 16 + l16) * C_ + quad * 8;
#pragma unroll
            for (int kc = 0; kc < 8; ++kc) {
                bf16x8 bf = *(const bf16x8*)(Wrow + kc * 32);
                acc[nt] = __builtin_amdgcn_mfma_f32_16x16x32_bf16(af[mt][kc], bf, acc[nt], 0, 0, 0);
            }
        }
        // stage this wave's 16x128 f32 tile (stride 132: 2-way banks, 16B rows)
#pragma unroll
        for (int nt = 0; nt < 8; ++nt)
#pragma unroll
            for (int i = 0; i < 4; ++i)
                myst[(quad * 4 + i) * 132 + nt * 16 + l16] = acc[nt][i];
        // read back row-major, store coalesced
#pragma unroll
        for (int rr = 0; rr < 8; ++rr) {
            const int row = rr * 2 + (lane >> 5);
            const int cd = (lane & 31) * 4;
            float4 t4 = *(const float4*)&myst[row * 132 + cd];
            const size_t gidx = (size_t)(m0 + mt * 16 + row) * C_ + n0 + cd;
            if (mat == 0) {
                *(float4*)(f0 + gidx) = t4;
            } else if (mat == 1) {
                *(float4*)(f1 + gidx) = t4;
            } else {
                ushort4 s4;
                s4.x = f2b(1.f / (1.f + __expf(-t4.x)));
                s4.y = f2b(1.f / (1.f + __expf(-t4.y)));
                s4.z = f2b(1.f / (1.f + __expf(-t4.z)));
                s4.w = f2b(1.f / (1.f + __expf(-t4.w)));
                *(ushort4*)(b2 + gidx) = s4;
            }
        }
    }
}

// ---------------- WKV pass 1: chunk-local states from zero init ----------------
__global__ __launch_bounds__(256) void wkv_pass1(const float* __restrict__ k,
                                                 const float* __restrict__ v,
                                                 const float* __restrict__ decay,
                                                 float* __restrict__ sp, float* __restrict__ sq,
                                                 float* __restrict__ so) {
    const int c = threadIdx.x, chunk = blockIdx.x, b = blockIdx.y;
    const float w = decay[c] * (1.0f / T_);
    size_t base = ((size_t)b * T_ + (size_t)chunk * L_) * C_ + c;
    float p = 0.f, q = 0.f, o = -1e38f;
    for (int t = 0; t < L_; t += 8) {
        float kk[8], vv[8];
#pragma unroll
        for (int j = 0; j < 8; ++j) {
            kk[j] = k[base + (size_t)(t + j) * C_];
            vv[j] = v[base + (size_t)(t + j) * C_];
        }
#pragma unroll
        for (int j = 0; j < 8; ++j) {
            float wo = w + o;
            float no = fmaxf(wo, kk[j]);
            float a2 = __expf(wo - no), b2 = __expf(kk[j] - no);
            p = a2 * p + b2 * vv[j];
            q = a2 * q + b2;
            o = no;
        }
    }
    size_t idx = ((size_t)b * NC_ + chunk) * C_ + c;
    sp[idx] = p; sq[idx] = q; so[idx] = o;
}

// ---------------- WKV pass 2 (inline prefix combine) + LayerNorm + gate --------
// Block = (chunk, b). Thread c first folds chunk-states 0..chunk-1 (L2-hot,
// <=127 iters) to get its true initial state, then scans its L_ timesteps,
// LayerNorm via LDS transpose, gates with sr, emits bf16 z.
__global__ __launch_bounds__(256) void wkv_pass2_ln(const float* __restrict__ k,
                                                    const float* __restrict__ v,
                                                    const unsigned short* __restrict__ sr,
                                                    const float* __restrict__ decay,
                                                    const float* __restrict__ first,
                                                    const float* __restrict__ lw,
                                                    const float* __restrict__ lb,
                                                    const float* __restrict__ sp,
                                                    const float* __restrict__ sq,
                                                    const float* __restrict__ so,
                                                    unsigned short* __restrict__ z) {
    __shared__ float tile[8][260];
    __shared__ float mu_s[8], rs_s[8];
    const int c = threadIdx.x, chunk = blockIdx.x, b = blockIdx.y;
    const int wave = c >> 6, lane = c & 63;
    const float w = decay[c] * (1.0f / T_);
    const float u = first[c] * (1.0f / T_);
    const float wL = w * (float)L_;
    const float gw = lw[c], gb = lb[c];

    // inline combine: fold states of chunks 0..chunk-1 (same order/arithmetic
    // as the old wkv_combine kernel -> bit-identical)
    float p = 0.f, q = 0.f, o = -1e38f;
    for (int ch = 0; ch < chunk; ++ch) {
        size_t idx = ((size_t)b * NC_ + ch) * C_ + c;
        float lp = sp[idx], lq = sq[idx], lo = so[idx];
        float ow = o + wL;
        float no = fmaxf(ow, lo);
        float ea = __expf(ow - no), eb = __expf(lo - no);
        p = ea * p + eb * lp;
        q = ea * q + eb * lq;
        o = no;
    }

    size_t base = ((size_t)b * T_ + (size_t)chunk * L_) * C_ + c;
    for (int t = 0; t < L_; t += 8) {
        float kk[8], vv[8], yy[8];
#pragma unroll
        for (int j = 0; j < 8; ++j) {
            kk[j] = k[base + (size_t)(t + j) * C_];
            vv[j] = v[base + (size_t)(t + j) * C_];
        }
#pragma unroll
        for (int j = 0; j < 8; ++j) {
            float uk = u + kk[j];
            float no = fmaxf(o, uk);
            float a = __expf(o - no), bb = __expf(uk - no);
            yy[j] = (a * p + bb * vv[j]) / (a * q + bb);
            float wo = w + o;
            float no2 = fmaxf(wo, kk[j]);
            float a2 = __expf(wo - no2), b2 = __expf(kk[j] - no2);
            p = a2 * p + b2 * vv[j];
            q = a2 * q + b2;
            o = no2;
        }
        __syncthreads();
#pragma unroll
        for (int j = 0; j < 8; ++j) tile[j][c] = yy[j];
        __syncthreads();
#pragma unroll
        for (int r = 0; r < 2; ++r) {
            const int j = wave * 2 + r;
            float4 t4 = *(const float4*)&tile[j][lane * 4];
            float s = t4.x + t4.y + t4.z + t4.w;
            float ss = t4.x * t4.x + t4.y * t4.y + t4.z * t4.z + t4.w * t4.w;
#pragma unroll
            for (int m = 1; m < 64; m <<= 1) {
                s += __shfl_xor(s, m, 64);
                ss += __shfl_xor(ss, m, 64);
            }
            if (lane == 0) {
                float mu = s * (1.f / C_);
                mu_s[j] = mu;
                rs_s[j] = rsqrtf(ss * (1.f / C_) - mu * mu + 1e-5f);
            }
        }
        __syncthreads();
#pragma unroll
        for (int j = 0; j < 8; ++j) {
            float zz = (yy[j] - mu_s[j]) * rs_s[j] * gw + gb;
            zz *= b2f(sr[base + (size_t)(t + j) * C_]);
            z[base + (size_t)(t + j) * C_] = f2b(zz);
        }
    }
}

extern "C" void kernel_launch(void* const* d_in, const int* in_sizes, int n_in,
                              void* d_out, int out_size, void* d_ws, size_t ws_size,
                              hipStream_t stream) {
    const float* x     = (const float*)d_in[0];
    const float* Wk    = (const float*)d_in[1];
    const float* Wv    = (const float*)d_in[2];
    const float* Wr    = (const float*)d_in[3];
    const float* Wo    = (const float*)d_in[4];
    const float* decay = (const float*)d_in[5];
    const float* first = (const float*)d_in[6];
    const float* lnw   = (const float*)d_in[7];
    const float* lnb   = (const float*)d_in[8];
    float* out = (float*)d_out;

    char* ws = (char*)d_ws;
    const size_t NE = (size_t)M_ * C_;              // 8388608
    unsigned short* wb  = (unsigned short*)ws; ws += 4 * 65536 * 2;  // wk|wv|wr|wo
    unsigned short* xb  = (unsigned short*)ws; ws += NE * 2;
    float* kbuf = (float*)ws; ws += NE * 4;
    float* vbuf = (float*)ws; ws += NE * 4;
    unsigned short* srb = (unsigned short*)ws; ws += NE * 2;
    unsigned short* zb  = (unsigned short*)ws; ws += NE * 2;
    const size_t SE = (size_t)B_ * NC_ * C_;        // 262144
    float* sp = (float*)ws; ws += SE * 4;
    float* sq = (float*)ws; ws += SE * 4;
    float* so = (float*)ws; ws += SE * 4;
    unsigned short* wkb = wb;
    unsigned short* wvb = wb + 65536;
    unsigned short* wrb = wb + 2 * 65536;
    unsigned short* wob = wb + 3 * 65536;

    cvt_all<<<4096 + 128, 256, 0, stream>>>(x, Wk, Wv, Wr, Wo, xb, wb);

    // QKV: 256 row-blocks x 2 col-halves x 3 mats = 1536 blocks
    gemm_tile<2><<<dim3(M_ / 128, 2, 3), 256, 0, stream>>>(xb, wkb, wvb, wrb,
                                                           kbuf, vbuf, srb);

    wkv_pass1<<<dim3(NC_, B_), 256, 0, stream>>>(kbuf, vbuf, decay, sp, sq, so);
    wkv_pass2_ln<<<dim3(NC_, B_), 256, 0, stream>>>(kbuf, vbuf, srb, decay, first,
                                                    lnw, lnb, sp, sq, so, zb);

    // Output GEMM: 512 row-blocks x 2 col-halves = 1024 blocks
    gemm_tile<1><<<dim3(M_ / 64, 2, 1), 256, 0, stream>>>(zb, wob, wob, wob,
                                                          out, nullptr, nullptr);
}

// Round 6
// 290.343 us; speedup vs baseline: 1.1197x; 1.1197x over previous
//
#include <hip/hip_runtime.h>
#include <cstdint>
#include <cstddef>

#define B_ 8
#define T_ 4096
#define C_ 256
#define NC_ 128
#define L_ (T_ / NC_)   // 32 steps per chunk
#define M_ (B_ * T_)    // 32768 rows

typedef float f32x4 __attribute__((ext_vector_type(4)));
typedef short bf16x8 __attribute__((ext_vector_type(8)));

__device__ __forceinline__ unsigned short f2b(float f) {
    unsigned int u = __float_as_uint(f);
    u += 0x7fffu + ((u >> 16) & 1u);   // round-to-nearest-even
    return (unsigned short)(u >> 16);
}
__device__ __forceinline__ float b2f(unsigned short h) {
    return __uint_as_float(((unsigned int)h) << 16);
}

// ---------------- fused f32->bf16 convert: x (4096 blocks) + 4 weights --------
// Each block converts 2048 elems. Weights are 65536 elems = 32 blocks each.
__global__ __launch_bounds__(256) void cvt_all(const float* __restrict__ x,
                                               const float* __restrict__ Wk,
                                               const float* __restrict__ Wv,
                                               const float* __restrict__ Wr,
                                               const float* __restrict__ Wo,
                                               unsigned short* __restrict__ xb,
                                               unsigned short* __restrict__ wb) {
    const int bid = blockIdx.x;
    const float* src;
    unsigned short* dst;
    size_t base;
    if (bid < 4096) {
        src = x; dst = xb;
        base = (size_t)bid * 2048;
    } else {
        const int r = bid - 4096;          // 0..127
        const int mat = r >> 5;            // 0..3
        src = (mat == 0) ? Wk : (mat == 1) ? Wv : (mat == 2) ? Wr : Wo;
        dst = wb + (size_t)mat * 65536;
        base = (size_t)(r & 31) * 2048;
    }
    const size_t i = base + (size_t)threadIdx.x * 8;
    float4 a = *(const float4*)(src + i);
    float4 b = *(const float4*)(src + i + 4);
    bf16x8 o;
    o[0] = (short)f2b(a.x); o[1] = (short)f2b(a.y);
    o[2] = (short)f2b(a.z); o[3] = (short)f2b(a.w);
    o[4] = (short)f2b(b.x); o[5] = (short)f2b(b.y);
    o[6] = (short)f2b(b.z); o[7] = (short)f2b(b.w);
    *(bf16x8*)(dst + i) = o;
}

// ---------------- Tiled GEMM: O[m,n] = sum_k A[m,k] * W[n,k] ------------------
// Wave: 16*MT rows x 64 cols. Block: 4 waves = 64*MT rows x 64 cols.
// grid = (M/(64*MT), 4 col-strips, n_mats). mat 0 -> f0 (f32), mat 1 -> f1
// (f32), mat 2 -> b2 (sigmoid, bf16).
// __launch_bounds__(256,4): VGPR cap 128 so af (32, per-mt) + acc (16) +
// 8 in-flight W loads (32) all stay resident -- fixes the R3/R5 pattern where
// a 60-64 VGPR budget forced A-frag reloads and serialized L2 loads.
// Epilogue: per-wave LDS stage (16 x 68 stride, 2-way banks = free) then
// row-major dwordx4 stores (4 rows x 256 B contiguous per wave-instr).
template <int MT>
__global__ __launch_bounds__(256, 4) void gemm_tile(const unsigned short* __restrict__ A,
                                                    const unsigned short* __restrict__ w0,
                                                    const unsigned short* __restrict__ w1,
                                                    const unsigned short* __restrict__ w2,
                                                    float* __restrict__ f0,
                                                    float* __restrict__ f1,
                                                    unsigned short* __restrict__ b2) {
    __shared__ float stage[4][16 * 68];
    const int wave = threadIdx.x >> 6, lane = threadIdx.x & 63;
    const int quad = lane >> 4, l16 = lane & 15;
    const int m0 = blockIdx.x * (64 * MT) + wave * (16 * MT);
    const int n0 = blockIdx.y * 64;
    const int mat = blockIdx.z;
    const unsigned short* W = (mat == 0) ? w0 : (mat == 1) ? w1 : w2;
    float* myst = stage[wave];

#pragma unroll
    for (int mt = 0; mt < MT; ++mt) {
        // A-frags for this 16-row tile only (32 VGPRs live)
        bf16x8 af[8];
        const unsigned short* Ar = A + (size_t)(m0 + mt * 16 + l16) * C_ + quad * 8;
#pragma unroll
        for (int kc = 0; kc < 8; ++kc) af[kc] = *(const bf16x8*)(Ar + kc * 32);

        f32x4 acc[4];
#pragma unroll
        for (int nt = 0; nt < 4; ++nt) acc[nt] = (f32x4){0.f, 0.f, 0.f, 0.f};
#pragma unroll
        for (int nt = 0; nt < 4; ++nt) {
            const unsigned short* Wrow = W + (size_t)(n0 + nt * 16 + l16) * C_ + quad * 8;
#pragma unroll
            for (int kc = 0; kc < 8; ++kc) {
                bf16x8 bf = *(const bf16x8*)(Wrow + kc * 32);
                acc[nt] = __builtin_amdgcn_mfma_f32_16x16x32_bf16(af[kc], bf, acc[nt], 0, 0, 0);
            }
        }
        // stage 16x64 f32 tile (stride 68: 2-way banks = free)
#pragma unroll
        for (int nt = 0; nt < 4; ++nt)
#pragma unroll
            for (int i = 0; i < 4; ++i)
                myst[(quad * 4 + i) * 68 + nt * 16 + l16] = acc[nt][i];
        // read back row-major, store coalesced (4 rows x 256 B per instr)
#pragma unroll
        for (int rr = 0; rr < 4; ++rr) {
            const int row = rr * 4 + quad;
            const int cd = l16 * 4;
            float4 t4 = *(const float4*)&myst[row * 68 + cd];
            const size_t gidx = (size_t)(m0 + mt * 16 + row) * C_ + n0 + cd;
            if (mat == 0) {
                *(float4*)(f0 + gidx) = t4;
            } else if (mat == 1) {
                *(float4*)(f1 + gidx) = t4;
            } else {
                ushort4 s4;
                s4.x = f2b(1.f / (1.f + __expf(-t4.x)));
                s4.y = f2b(1.f / (1.f + __expf(-t4.y)));
                s4.z = f2b(1.f / (1.f + __expf(-t4.z)));
                s4.w = f2b(1.f / (1.f + __expf(-t4.w)));
                *(ushort4*)(b2 + gidx) = s4;
            }
        }
    }
}

// ---------------- WKV pass 1: chunk-local states from zero init ----------------
__global__ __launch_bounds__(256) void wkv_pass1(const float* __restrict__ k,
                                                 const float* __restrict__ v,
                                                 const float* __restrict__ decay,
                                                 float* __restrict__ sp, float* __restrict__ sq,
                                                 float* __restrict__ so) {
    const int c = threadIdx.x, chunk = blockIdx.x, b = blockIdx.y;
    const float w = decay[c] * (1.0f / T_);
    size_t base = ((size_t)b * T_ + (size_t)chunk * L_) * C_ + c;
    float p = 0.f, q = 0.f, o = -1e38f;
    for (int t = 0; t < L_; t += 8) {
        float kk[8], vv[8];
#pragma unroll
        for (int j = 0; j < 8; ++j) {
            kk[j] = k[base + (size_t)(t + j) * C_];
            vv[j] = v[base + (size_t)(t + j) * C_];
        }
#pragma unroll
        for (int j = 0; j < 8; ++j) {
            float wo = w + o;
            float no = fmaxf(wo, kk[j]);
            float a2 = __expf(wo - no), b2 = __expf(kk[j] - no);
            p = a2 * p + b2 * vv[j];
            q = a2 * q + b2;
            o = no;
        }
    }
    size_t idx = ((size_t)b * NC_ + chunk) * C_ + c;
    sp[idx] = p; sq[idx] = q; so[idx] = o;
}

// ---------------- WKV pass 2 (inline prefix combine) + LayerNorm + gate --------
// Block = (chunk, b). Thread c first folds chunk-states 0..chunk-1 (L2-hot,
// <=127 iters) to get its true initial state, then scans its L_ timesteps,
// LayerNorm via LDS transpose, gates with sr, emits bf16 z.
__global__ __launch_bounds__(256) void wkv_pass2_ln(const float* __restrict__ k,
                                                    const float* __restrict__ v,
                                                    const unsigned short* __restrict__ sr,
                                                    const float* __restrict__ decay,
                                                    const float* __restrict__ first,
                                                    const float* __restrict__ lw,
                                                    const float* __restrict__ lb,
                                                    const float* __restrict__ sp,
                                                    const float* __restrict__ sq,
                                                    const float* __restrict__ so,
                                                    unsigned short* __restrict__ z) {
    __shared__ float tile[8][260];
    __shared__ float mu_s[8], rs_s[8];
    const int c = threadIdx.x, chunk = blockIdx.x, b = blockIdx.y;
    const int wave = c >> 6, lane = c & 63;
    const float w = decay[c] * (1.0f / T_);
    const float u = first[c] * (1.0f / T_);
    const float wL = w * (float)L_;
    const float gw = lw[c], gb = lb[c];

    // inline combine: fold states of chunks 0..chunk-1 (same order/arithmetic
    // as a standalone combine kernel -> bit-identical)
    float p = 0.f, q = 0.f, o = -1e38f;
    for (int ch = 0; ch < chunk; ++ch) {
        size_t idx = ((size_t)b * NC_ + ch) * C_ + c;
        float lp = sp[idx], lq = sq[idx], lo = so[idx];
        float ow = o + wL;
        float no = fmaxf(ow, lo);
        float ea = __expf(ow - no), eb = __expf(lo - no);
        p = ea * p + eb * lp;
        q = ea * q + eb * lq;
        o = no;
    }

    size_t base = ((size_t)b * T_ + (size_t)chunk * L_) * C_ + c;
    for (int t = 0; t < L_; t += 8) {
        float kk[8], vv[8], yy[8];
#pragma unroll
        for (int j = 0; j < 8; ++j) {
            kk[j] = k[base + (size_t)(t + j) * C_];
            vv[j] = v[base + (size_t)(t + j) * C_];
        }
#pragma unroll
        for (int j = 0; j < 8; ++j) {
            float uk = u + kk[j];
            float no = fmaxf(o, uk);
            float a = __expf(o - no), bb = __expf(uk - no);
            yy[j] = (a * p + bb * vv[j]) / (a * q + bb);
            float wo = w + o;
            float no2 = fmaxf(wo, kk[j]);
            float a2 = __expf(wo - no2), b2 = __expf(kk[j] - no2);
            p = a2 * p + b2 * vv[j];
            q = a2 * q + b2;
            o = no2;
        }
        __syncthreads();
#pragma unroll
        for (int j = 0; j < 8; ++j) tile[j][c] = yy[j];
        __syncthreads();
#pragma unroll
        for (int r = 0; r < 2; ++r) {
            const int j = wave * 2 + r;
            float4 t4 = *(const float4*)&tile[j][lane * 4];
            float s = t4.x + t4.y + t4.z + t4.w;
            float ss = t4.x * t4.x + t4.y * t4.y + t4.z * t4.z + t4.w * t4.w;
#pragma unroll
            for (int m = 1; m < 64; m <<= 1) {
                s += __shfl_xor(s, m, 64);
                ss += __shfl_xor(ss, m, 64);
            }
            if (lane == 0) {
                float mu = s * (1.f / C_);
                mu_s[j] = mu;
                rs_s[j] = rsqrtf(ss * (1.f / C_) - mu * mu + 1e-5f);
            }
        }
        __syncthreads();
#pragma unroll
        for (int j = 0; j < 8; ++j) {
            float zz = (yy[j] - mu_s[j]) * rs_s[j] * gw + gb;
            zz *= b2f(sr[base + (size_t)(t + j) * C_]);
            z[base + (size_t)(t + j) * C_] = f2b(zz);
        }
    }
}

extern "C" void kernel_launch(void* const* d_in, const int* in_sizes, int n_in,
                              void* d_out, int out_size, void* d_ws, size_t ws_size,
                              hipStream_t stream) {
    const float* x     = (const float*)d_in[0];
    const float* Wk    = (const float*)d_in[1];
    const float* Wv    = (const float*)d_in[2];
    const float* Wr    = (const float*)d_in[3];
    const float* Wo    = (const float*)d_in[4];
    const float* decay = (const float*)d_in[5];
    const float* first = (const float*)d_in[6];
    const float* lnw   = (const float*)d_in[7];
    const float* lnb   = (const float*)d_in[8];
    float* out = (float*)d_out;

    char* ws = (char*)d_ws;
    const size_t NE = (size_t)M_ * C_;              // 8388608
    unsigned short* wb  = (unsigned short*)ws; ws += 4 * 65536 * 2;  // wk|wv|wr|wo
    unsigned short* xb  = (unsigned short*)ws; ws += NE * 2;
    float* kbuf = (float*)ws; ws += NE * 4;
    float* vbuf = (float*)ws; ws += NE * 4;
    unsigned short* srb = (unsigned short*)ws; ws += NE * 2;
    unsigned short* zb  = (unsigned short*)ws; ws += NE * 2;
    const size_t SE = (size_t)B_ * NC_ * C_;        // 262144
    float* sp = (float*)ws; ws += SE * 4;
    float* sq = (float*)ws; ws += SE * 4;
    float* so = (float*)ws; ws += SE * 4;
    unsigned short* wkb = wb;
    unsigned short* wvb = wb + 65536;
    unsigned short* wrb = wb + 2 * 65536;
    unsigned short* wob = wb + 3 * 65536;

    cvt_all<<<4096 + 128, 256, 0, stream>>>(x, Wk, Wv, Wr, Wo, xb, wb);

    // QKV: 256 row-blocks x 4 col-strips x 3 mats = 3072 blocks
    gemm_tile<2><<<dim3(M_ / 128, 4, 3), 256, 0, stream>>>(xb, wkb, wvb, wrb,
                                                           kbuf, vbuf, srb);

    wkv_pass1<<<dim3(NC_, B_), 256, 0, stream>>>(kbuf, vbuf, decay, sp, sq, so);
    wkv_pass2_ln<<<dim3(NC_, B_), 256, 0, stream>>>(kbuf, vbuf, srb, decay, first,
                                                    lnw, lnb, sp, sq, so, zb);

    // Output GEMM: 256 row-blocks x 4 col-strips = 1024 blocks
    gemm_tile<2><<<dim3(M_ / 128, 4, 1), 256, 0, stream>>>(zb, wob, wob, wob,
                                                           out, nullptr, nullptr);
}

// Round 7
// 215.755 us; speedup vs baseline: 1.5068x; 1.3457x over previous
//
#include <hip/hip_runtime.h>
#include <cstdint>
#include <cstddef>

#define B_ 8
#define T_ 4096
#define C_ 256
#define NC_ 128
#define L_ (T_ / NC_)   // 32 steps per chunk
#define M_ (B_ * T_)    // 32768 rows

typedef float f32x4 __attribute__((ext_vector_type(4)));
typedef short bf16x8 __attribute__((ext_vector_type(8)));

__device__ __forceinline__ unsigned short f2b(float f) {
    unsigned int u = __float_as_uint(f);
    u += 0x7fffu + ((u >> 16) & 1u);   // round-to-nearest-even
    return (unsigned short)(u >> 16);
}
__device__ __forceinline__ float b2f(unsigned short h) {
    return __uint_as_float(((unsigned int)h) << 16);
}

// ---------------- fused f32->bf16 convert: x (4096 blocks) + 4 weights --------
// Each block converts 2048 elems. Weights are 65536 elems = 32 blocks each.
__global__ __launch_bounds__(256) void cvt_all(const float* __restrict__ x,
                                               const float* __restrict__ Wk,
                                               const float* __restrict__ Wv,
                                               const float* __restrict__ Wr,
                                               const float* __restrict__ Wo,
                                               unsigned short* __restrict__ xb,
                                               unsigned short* __restrict__ wb) {
    const int bid = blockIdx.x;
    const float* src;
    unsigned short* dst;
    size_t base;
    if (bid < 4096) {
        src = x; dst = xb;
        base = (size_t)bid * 2048;
    } else {
        const int r = bid - 4096;          // 0..127
        const int mat = r >> 5;            // 0..3
        src = (mat == 0) ? Wk : (mat == 1) ? Wv : (mat == 2) ? Wr : Wo;
        dst = wb + (size_t)mat * 65536;
        base = (size_t)(r & 31) * 2048;
    }
    const size_t i = base + (size_t)threadIdx.x * 8;
    float4 a = *(const float4*)(src + i);
    float4 b = *(const float4*)(src + i + 4);
    bf16x8 o;
    o[0] = (short)f2b(a.x); o[1] = (short)f2b(a.y);
    o[2] = (short)f2b(a.z); o[3] = (short)f2b(a.w);
    o[4] = (short)f2b(b.x); o[5] = (short)f2b(b.y);
    o[6] = (short)f2b(b.z); o[7] = (short)f2b(b.w);
    *(bf16x8*)(dst + i) = o;
}

// ---------------- GEMM, W-in-LDS streaming: O[m,n] = sum_k A[m,k]*W[n,k] ------
// Block: 128 rows x 64-col strip. Stage the strip's W (64 rows x 256 K bf16,
// padded row stride 264 shorts) into LDS ONCE (one barrier), then each wave
// streams 2 independent 16-row A-tiles: 8 native-frag global A-loads +
// 32 ds_read_b128 + 32 MFMA. No barrier in the compute loop. This removes
// the global-latency serialization that capped R2-R6 (compiler pipelines
// ds_read->MFMA well; it refuses to pipeline global->VGPR operand loads).
// Epilogue: per-wave LDS stage then 4-row x 256 B contiguous stores.
// mat 0 -> f0 (f32), 1 -> f1 (f32), 2 -> b2 (sigmoid, bf16).
__global__ __launch_bounds__(256, 3) void gemm_wlds(const unsigned short* __restrict__ A,
                                                    const unsigned short* __restrict__ w0,
                                                    const unsigned short* __restrict__ w1,
                                                    const unsigned short* __restrict__ w2,
                                                    float* __restrict__ f0,
                                                    float* __restrict__ f1,
                                                    unsigned short* __restrict__ b2) {
    __shared__ unsigned short wlds[64 * 264];   // 33792 B
    __shared__ float stage[4][16 * 68];         // 17408 B  (total 51200 B -> 3 blk/CU)
    const int tid = threadIdx.x;
    const int wave = tid >> 6, lane = tid & 63;
    const int quad = lane >> 4, l16 = lane & 15;
    const int m0 = blockIdx.x * 128 + wave * 32;   // 2 m-tiles of 16 per wave
    const int n0 = blockIdx.y * 64;
    const int mat = blockIdx.z;
    const unsigned short* W = (mat == 0) ? w0 : (mat == 1) ? w1 : w2;
    float* myst = stage[wave];

    // ---- stage W strip: 64 rows x 512 B, coalesced 4 KB per iteration ----
    {
        const int r = tid >> 5;              // 0..7
        const int cs = (tid & 31) * 8;       // short offset, 16 B per lane
        bf16x8 tmp[8];
#pragma unroll
        for (int it = 0; it < 8; ++it)
            tmp[it] = *(const bf16x8*)(W + (size_t)(n0 + it * 8 + r) * C_ + cs);
#pragma unroll
        for (int it = 0; it < 8; ++it)
            *(bf16x8*)(wlds + (it * 8 + r) * 264 + cs) = tmp[it];
    }
    __syncthreads();

#pragma unroll
    for (int mt = 0; mt < 2; ++mt) {
        // A-frags, native MFMA layout: lane(l16,quad) -> A[m0+mt*16+l16][quad*8+kc*32..+8]
        const unsigned short* Ar = A + (size_t)(m0 + mt * 16 + l16) * C_ + quad * 8;
        bf16x8 af[8];
#pragma unroll
        for (int kc = 0; kc < 8; ++kc) af[kc] = *(const bf16x8*)(Ar + kc * 32);

        f32x4 acc[4];
#pragma unroll
        for (int nt = 0; nt < 4; ++nt) acc[nt] = (f32x4){0.f, 0.f, 0.f, 0.f};
#pragma unroll
        for (int nt = 0; nt < 4; ++nt) {
            const unsigned short* wrow = wlds + (nt * 16 + l16) * 264 + quad * 8;
#pragma unroll
            for (int kc = 0; kc < 8; ++kc) {
                bf16x8 wf = *(const bf16x8*)(wrow + kc * 32);
                acc[nt] = __builtin_amdgcn_mfma_f32_16x16x32_bf16(af[kc], wf, acc[nt], 0, 0, 0);
            }
        }

        // ---- epilogue: per-wave LDS transpose, then 256 B-contiguous stores ----
#pragma unroll
        for (int nt = 0; nt < 4; ++nt)
#pragma unroll
            for (int i = 0; i < 4; ++i)
                myst[(quad * 4 + i) * 68 + nt * 16 + l16] = acc[nt][i];
#pragma unroll
        for (int rr = 0; rr < 4; ++rr) {
            const int row = rr * 4 + quad;
            float4 t4 = *(const float4*)&myst[row * 68 + l16 * 4];
            const size_t gidx = (size_t)(m0 + mt * 16 + row) * C_ + n0 + l16 * 4;
            if (mat == 0) {
                *(float4*)(f0 + gidx) = t4;
            } else if (mat == 1) {
                *(float4*)(f1 + gidx) = t4;
            } else {
                ushort4 s4;
                s4.x = f2b(1.f / (1.f + __expf(-t4.x)));
                s4.y = f2b(1.f / (1.f + __expf(-t4.y)));
                s4.z = f2b(1.f / (1.f + __expf(-t4.z)));
                s4.w = f2b(1.f / (1.f + __expf(-t4.w)));
                *(ushort4*)(b2 + gidx) = s4;
            }
        }
    }
}

// ---------------- WKV pass 1: chunk-local states from zero init ----------------
__global__ __launch_bounds__(256) void wkv_pass1(const float* __restrict__ k,
                                                 const float* __restrict__ v,
                                                 const float* __restrict__ decay,
                                                 float* __restrict__ sp, float* __restrict__ sq,
                                                 float* __restrict__ so) {
    const int c = threadIdx.x, chunk = blockIdx.x, b = blockIdx.y;
    const float w = decay[c] * (1.0f / T_);
    size_t base = ((size_t)b * T_ + (size_t)chunk * L_) * C_ + c;
    float p = 0.f, q = 0.f, o = -1e38f;
    for (int t = 0; t < L_; t += 8) {
        float kk[8], vv[8];
#pragma unroll
        for (int j = 0; j < 8; ++j) {
            kk[j] = k[base + (size_t)(t + j) * C_];
            vv[j] = v[base + (size_t)(t + j) * C_];
        }
#pragma unroll
        for (int j = 0; j < 8; ++j) {
            float wo = w + o;
            float no = fmaxf(wo, kk[j]);
            float a2 = __expf(wo - no), b2 = __expf(kk[j] - no);
            p = a2 * p + b2 * vv[j];
            q = a2 * q + b2;
            o = no;
        }
    }
    size_t idx = ((size_t)b * NC_ + chunk) * C_ + c;
    sp[idx] = p; sq[idx] = q; so[idx] = o;
}

// ---------------- WKV pass 2 (inline prefix combine) + LayerNorm + gate --------
__global__ __launch_bounds__(256) void wkv_pass2_ln(const float* __restrict__ k,
                                                    const float* __restrict__ v,
                                                    const unsigned short* __restrict__ sr,
                                                    const float* __restrict__ decay,
                                                    const float* __restrict__ first,
                                                    const float* __restrict__ lw,
                                                    const float* __restrict__ lb,
                                                    const float* __restrict__ sp,
                                                    const float* __restrict__ sq,
                                                    const float* __restrict__ so,
                                                    unsigned short* __restrict__ z) {
    __shared__ float tile[8][260];
    __shared__ float mu_s[8], rs_s[8];
    const int c = threadIdx.x, chunk = blockIdx.x, b = blockIdx.y;
    const int wave = c >> 6, lane = c & 63;
    const float w = decay[c] * (1.0f / T_);
    const float u = first[c] * (1.0f / T_);
    const float wL = w * (float)L_;
    const float gw = lw[c], gb = lb[c];

    float p = 0.f, q = 0.f, o = -1e38f;
    for (int ch = 0; ch < chunk; ++ch) {
        size_t idx = ((size_t)b * NC_ + ch) * C_ + c;
        float lp = sp[idx], lq = sq[idx], lo = so[idx];
        float ow = o + wL;
        float no = fmaxf(ow, lo);
        float ea = __expf(ow - no), eb = __expf(lo - no);
        p = ea * p + eb * lp;
        q = ea * q + eb * lq;
        o = no;
    }

    size_t base = ((size_t)b * T_ + (size_t)chunk * L_) * C_ + c;
    for (int t = 0; t < L_; t += 8) {
        float kk[8], vv[8], yy[8];
#pragma unroll
        for (int j = 0; j < 8; ++j) {
            kk[j] = k[base + (size_t)(t + j) * C_];
            vv[j] = v[base + (size_t)(t + j) * C_];
        }
#pragma unroll
        for (int j = 0; j < 8; ++j) {
            float uk = u + kk[j];
            float no = fmaxf(o, uk);
            float a = __expf(o - no), bb = __expf(uk - no);
            yy[j] = (a * p + bb * vv[j]) / (a * q + bb);
            float wo = w + o;
            float no2 = fmaxf(wo, kk[j]);
            float a2 = __expf(wo - no2), b2 = __expf(kk[j] - no2);
            p = a2 * p + b2 * vv[j];
            q = a2 * q + b2;
            o = no2;
        }
        __syncthreads();
#pragma unroll
        for (int j = 0; j < 8; ++j) tile[j][c] = yy[j];
        __syncthreads();
#pragma unroll
        for (int r = 0; r < 2; ++r) {
            const int j = wave * 2 + r;
            float4 t4 = *(const float4*)&tile[j][lane * 4];
            float s = t4.x + t4.y + t4.z + t4.w;
            float ss = t4.x * t4.x + t4.y * t4.y + t4.z * t4.z + t4.w * t4.w;
#pragma unroll
            for (int m = 1; m < 64; m <<= 1) {
                s += __shfl_xor(s, m, 64);
                ss += __shfl_xor(ss, m, 64);
            }
            if (lane == 0) {
                float mu = s * (1.f / C_);
                mu_s[j] = mu;
                rs_s[j] = rsqrtf(ss * (1.f / C_) - mu * mu + 1e-5f);
            }
        }
        __syncthreads();
#pragma unroll
        for (int j = 0; j < 8; ++j) {
            float zz = (yy[j] - mu_s[j]) * rs_s[j] * gw + gb;
            zz *= b2f(sr[base + (size_t)(t + j) * C_]);
            z[base + (size_t)(t + j) * C_] = f2b(zz);
        }
    }
}

extern "C" void kernel_launch(void* const* d_in, const int* in_sizes, int n_in,
                              void* d_out, int out_size, void* d_ws, size_t ws_size,
                              hipStream_t stream) {
    const float* x     = (const float*)d_in[0];
    const float* Wk    = (const float*)d_in[1];
    const float* Wv    = (const float*)d_in[2];
    const float* Wr    = (const float*)d_in[3];
    const float* Wo    = (const float*)d_in[4];
    const float* decay = (const float*)d_in[5];
    const float* first = (const float*)d_in[6];
    const float* lnw   = (const float*)d_in[7];
    const float* lnb   = (const float*)d_in[8];
    float* out = (float*)d_out;

    char* ws = (char*)d_ws;
    const size_t NE = (size_t)M_ * C_;              // 8388608
    unsigned short* wb  = (unsigned short*)ws; ws += 4 * 65536 * 2;  // wk|wv|wr|wo
    unsigned short* xb  = (unsigned short*)ws; ws += NE * 2;
    float* kbuf = (float*)ws; ws += NE * 4;
    float* vbuf = (float*)ws; ws += NE * 4;
    unsigned short* srb = (unsigned short*)ws; ws += NE * 2;
    unsigned short* zb  = (unsigned short*)ws; ws += NE * 2;
    const size_t SE = (size_t)B_ * NC_ * C_;        // 262144
    float* sp = (float*)ws; ws += SE * 4;
    float* sq = (float*)ws; ws += SE * 4;
    float* so = (float*)ws; ws += SE * 4;
    unsigned short* wkb = wb;
    unsigned short* wvb = wb + 65536;
    unsigned short* wrb = wb + 2 * 65536;
    unsigned short* wob = wb + 3 * 65536;

    cvt_all<<<4096 + 128, 256, 0, stream>>>(x, Wk, Wv, Wr, Wo, xb, wb);

    // QKV: 256 row-blocks x 4 col-strips x 3 mats = 3072 blocks
    gemm_wlds<<<dim3(M_ / 128, 4, 3), 256, 0, stream>>>(xb, wkb, wvb, wrb,
                                                        kbuf, vbuf, srb);

    wkv_pass1<<<dim3(NC_, B_), 256, 0, stream>>>(kbuf, vbuf, decay, sp, sq, so);
    wkv_pass2_ln<<<dim3(NC_, B_), 256, 0, stream>>>(kbuf, vbuf, srb, decay, first,
                                                    lnw, lnb, sp, sq, so, zb);

    // Output GEMM: 256 row-blocks x 4 col-strips = 1024 blocks
    gemm_wlds<<<dim3(M_ / 128, 4, 1), 256, 0, stream>>>(zb, wob, wob, wob,
                                                        out, nullptr, nullptr);
}

// Round 8
// 197.092 us; speedup vs baseline: 1.6495x; 1.0947x over previous
//
#include <hip/hip_runtime.h>
#include <cstdint>
#include <cstddef>

#define B_ 8
#define T_ 4096
#define C_ 256
#define NC_ 256
#define L_ (T_ / NC_)   // 16 steps per chunk
#define M_ (B_ * T_)    // 32768 rows

typedef float f32x4 __attribute__((ext_vector_type(4)));
typedef short bf16x8 __attribute__((ext_vector_type(8)));

__device__ __forceinline__ unsigned short f2b(float f) {
    unsigned int u = __float_as_uint(f);
    u += 0x7fffu + ((u >> 16) & 1u);   // round-to-nearest-even
    return (unsigned short)(u >> 16);
}
__device__ __forceinline__ float b2f(unsigned short h) {
    return __uint_as_float(((unsigned int)h) << 16);
}

// ---------------- fused f32->bf16 convert: x (4096 blocks) + 4 weights --------
// Each block converts 2048 elems. Weights are 65536 elems = 32 blocks each.
__global__ __launch_bounds__(256) void cvt_all(const float* __restrict__ x,
                                               const float* __restrict__ Wk,
                                               const float* __restrict__ Wv,
                                               const float* __restrict__ Wr,
                                               const float* __restrict__ Wo,
                                               unsigned short* __restrict__ xb,
                                               unsigned short* __restrict__ wb) {
    const int bid = blockIdx.x;
    const float* src;
    unsigned short* dst;
    size_t base;
    if (bid < 4096) {
        src = x; dst = xb;
        base = (size_t)bid * 2048;
    } else {
        const int r = bid - 4096;          // 0..127
        const int mat = r >> 5;            // 0..3
        src = (mat == 0) ? Wk : (mat == 1) ? Wv : (mat == 2) ? Wr : Wo;
        dst = wb + (size_t)mat * 65536;
        base = (size_t)(r & 31) * 2048;
    }
    const size_t i = base + (size_t)threadIdx.x * 8;
    float4 a = *(const float4*)(src + i);
    float4 b = *(const float4*)(src + i + 4);
    bf16x8 o;
    o[0] = (short)f2b(a.x); o[1] = (short)f2b(a.y);
    o[2] = (short)f2b(a.z); o[3] = (short)f2b(a.w);
    o[4] = (short)f2b(b.x); o[5] = (short)f2b(b.y);
    o[6] = (short)f2b(b.z); o[7] = (short)f2b(b.w);
    *(bf16x8*)(dst + i) = o;
}

// ---------------- GEMM, W-in-LDS streaming: O[m,n] = sum_k A[m,k]*W[n,k] ------
// (unchanged from R7 -- confirmed fast/correct)
__global__ __launch_bounds__(256, 3) void gemm_wlds(const unsigned short* __restrict__ A,
                                                    const unsigned short* __restrict__ w0,
                                                    const unsigned short* __restrict__ w1,
                                                    const unsigned short* __restrict__ w2,
                                                    float* __restrict__ f0,
                                                    float* __restrict__ f1,
                                                    unsigned short* __restrict__ b2) {
    __shared__ unsigned short wlds[64 * 264];   // 33792 B
    __shared__ float stage[4][16 * 68];         // 17408 B  (total 51200 B -> 3 blk/CU)
    const int tid = threadIdx.x;
    const int wave = tid >> 6, lane = tid & 63;
    const int quad = lane >> 4, l16 = lane & 15;
    const int m0 = blockIdx.x * 128 + wave * 32;   // 2 m-tiles of 16 per wave
    const int n0 = blockIdx.y * 64;
    const int mat = blockIdx.z;
    const unsigned short* W = (mat == 0) ? w0 : (mat == 1) ? w1 : w2;
    float* myst = stage[wave];

    {
        const int r = tid >> 5;              // 0..7
        const int cs = (tid & 31) * 8;       // short offset, 16 B per lane
        bf16x8 tmp[8];
#pragma unroll
        for (int it = 0; it < 8; ++it)
            tmp[it] = *(const bf16x8*)(W + (size_t)(n0 + it * 8 + r) * C_ + cs);
#pragma unroll
        for (int it = 0; it < 8; ++it)
            *(bf16x8*)(wlds + (it * 8 + r) * 264 + cs) = tmp[it];
    }
    __syncthreads();

#pragma unroll
    for (int mt = 0; mt < 2; ++mt) {
        const unsigned short* Ar = A + (size_t)(m0 + mt * 16 + l16) * C_ + quad * 8;
        bf16x8 af[8];
#pragma unroll
        for (int kc = 0; kc < 8; ++kc) af[kc] = *(const bf16x8*)(Ar + kc * 32);

        f32x4 acc[4];
#pragma unroll
        for (int nt = 0; nt < 4; ++nt) acc[nt] = (f32x4){0.f, 0.f, 0.f, 0.f};
#pragma unroll
        for (int nt = 0; nt < 4; ++nt) {
            const unsigned short* wrow = wlds + (nt * 16 + l16) * 264 + quad * 8;
#pragma unroll
            for (int kc = 0; kc < 8; ++kc) {
                bf16x8 wf = *(const bf16x8*)(wrow + kc * 32);
                acc[nt] = __builtin_amdgcn_mfma_f32_16x16x32_bf16(af[kc], wf, acc[nt], 0, 0, 0);
            }
        }

#pragma unroll
        for (int nt = 0; nt < 4; ++nt)
#pragma unroll
            for (int i = 0; i < 4; ++i)
                myst[(quad * 4 + i) * 68 + nt * 16 + l16] = acc[nt][i];
#pragma unroll
        for (int rr = 0; rr < 4; ++rr) {
            const int row = rr * 4 + quad;
            float4 t4 = *(const float4*)&myst[row * 68 + l16 * 4];
            const size_t gidx = (size_t)(m0 + mt * 16 + row) * C_ + n0 + l16 * 4;
            if (mat == 0) {
                *(float4*)(f0 + gidx) = t4;
            } else if (mat == 1) {
                *(float4*)(f1 + gidx) = t4;
            } else {
                ushort4 s4;
                s4.x = f2b(1.f / (1.f + __expf(-t4.x)));
                s4.y = f2b(1.f / (1.f + __expf(-t4.y)));
                s4.z = f2b(1.f / (1.f + __expf(-t4.z)));
                s4.w = f2b(1.f / (1.f + __expf(-t4.w)));
                *(ushort4*)(b2 + gidx) = s4;
            }
        }
    }
}

// ---------------- WKV pass 1: chunk-local states from zero init ----------------
__global__ __launch_bounds__(256) void wkv_pass1(const float* __restrict__ k,
                                                 const float* __restrict__ v,
                                                 const float* __restrict__ decay,
                                                 float* __restrict__ sp, float* __restrict__ sq,
                                                 float* __restrict__ so) {
    const int c = threadIdx.x, chunk = blockIdx.x, b = blockIdx.y;
    const float w = decay[c] * (1.0f / T_);
    size_t base = ((size_t)b * T_ + (size_t)chunk * L_) * C_ + c;
    float p = 0.f, q = 0.f, o = -1e38f;
    for (int t = 0; t < L_; t += 8) {
        float kk[8], vv[8];
#pragma unroll
        for (int j = 0; j < 8; ++j) {
            kk[j] = k[base + (size_t)(t + j) * C_];
            vv[j] = v[base + (size_t)(t + j) * C_];
        }
#pragma unroll
        for (int j = 0; j < 8; ++j) {
            float wo = w + o;
            float no = fmaxf(wo, kk[j]);
            float a2 = __expf(wo - no), b2 = __expf(kk[j] - no);
            p = a2 * p + b2 * vv[j];
            q = a2 * q + b2;
            o = no;
        }
    }
    size_t idx = ((size_t)b * NC_ + chunk) * C_ + c;
    sp[idx] = p; sq[idx] = q; so[idx] = o;
}

// ---------------- WKV combine: serial over chunks, IN-PLACE prefix ------------
// After this kernel, sp/sq/so[b,ch,c] hold the state BEFORE chunk ch
// (exclusive prefix). Each thread owns its c-column slots -> no races.
__global__ __launch_bounds__(256) void wkv_combine(const float* __restrict__ decay,
                                                   float* __restrict__ sp,
                                                   float* __restrict__ sq,
                                                   float* __restrict__ so) {
    const int c = threadIdx.x, b = blockIdx.x;
    const float wL = decay[c] * (1.0f / T_) * (float)L_;
    float p = 0.f, q = 0.f, o = -1e38f;
    for (int ch = 0; ch < NC_; ch += 8) {
        float lp[8], lq[8], lo[8];
#pragma unroll
        for (int j = 0; j < 8; ++j) {
            size_t idx = ((size_t)b * NC_ + ch + j) * C_ + c;
            lp[j] = sp[idx]; lq[j] = sq[idx]; lo[j] = so[idx];
        }
#pragma unroll
        for (int j = 0; j < 8; ++j) {
            size_t idx = ((size_t)b * NC_ + ch + j) * C_ + c;
            sp[idx] = p; sq[idx] = q; so[idx] = o;   // exclusive prefix
            float ow = o + wL;
            float no = fmaxf(ow, lo[j]);
            float ea = __expf(ow - no), eb = __expf(lo[j] - no);
            p = ea * p + eb * lp[j];
            q = ea * q + eb * lq[j];
            o = no;
        }
    }
}

// ---------------- WKV pass 2 + LayerNorm + gate (2 barriers total) -------------
// Block = (chunk, b); thread = channel. L_=16 steps: y goes straight into the
// LDS tile during the scan (no yy[] registers live across phases), one barrier,
// per-wave LN reduce of 4 rows, one barrier, gate + coalesced bf16 store.
__global__ __launch_bounds__(256, 8) void wkv_pass2_ln(const float* __restrict__ k,
                                                       const float* __restrict__ v,
                                                       const unsigned short* __restrict__ sr,
                                                       const float* __restrict__ decay,
                                                       const float* __restrict__ first,
                                                       const float* __restrict__ lw,
                                                       const float* __restrict__ lb,
                                                       const float* __restrict__ sp,
                                                       const float* __restrict__ sq,
                                                       const float* __restrict__ so,
                                                       unsigned short* __restrict__ z) {
    __shared__ float tile[16][264];
    __shared__ float mu_s[16], rs_s[16];
    const int c = threadIdx.x, chunk = blockIdx.x, b = blockIdx.y;
    const int wave = c >> 6, lane = c & 63;
    const float w = decay[c] * (1.0f / T_);
    const float u = first[c] * (1.0f / T_);
    const float gw = lw[c], gb = lb[c];
    size_t sidx = ((size_t)b * NC_ + chunk) * C_ + c;
    float p = sp[sidx], q = sq[sidx], o = so[sidx];
    size_t base = ((size_t)b * T_ + (size_t)chunk * L_) * C_ + c;

    for (int t = 0; t < L_; t += 8) {
        float kk[8], vv[8];
#pragma unroll
        for (int j = 0; j < 8; ++j) {
            kk[j] = k[base + (size_t)(t + j) * C_];
            vv[j] = v[base + (size_t)(t + j) * C_];
        }
#pragma unroll
        for (int j = 0; j < 8; ++j) {
            float uk = u + kk[j];
            float no = fmaxf(o, uk);
            float a = __expf(o - no), bb = __expf(uk - no);
            tile[t + j][c] = (a * p + bb * vv[j]) / (a * q + bb);
            float wo = w + o;
            float no2 = fmaxf(wo, kk[j]);
            float a2 = __expf(wo - no2), b2 = __expf(kk[j] - no2);
            p = a2 * p + b2 * vv[j];
            q = a2 * q + b2;
            o = no2;
        }
    }
    __syncthreads();
    // LN stats: wave handles rows wave*4 .. wave*4+3
#pragma unroll
    for (int r = 0; r < 4; ++r) {
        const int j = wave * 4 + r;
        float4 t4 = *(const float4*)&tile[j][lane * 4];
        float s = t4.x + t4.y + t4.z + t4.w;
        float ss = t4.x * t4.x + t4.y * t4.y + t4.z * t4.z + t4.w * t4.w;
#pragma unroll
        for (int m = 1; m < 64; m <<= 1) {
            s += __shfl_xor(s, m, 64);
            ss += __shfl_xor(ss, m, 64);
        }
        if (lane == 0) {
            float mu = s * (1.f / C_);
            mu_s[j] = mu;
            rs_s[j] = rsqrtf(ss * (1.f / C_) - mu * mu + 1e-5f);
        }
    }
    __syncthreads();
#pragma unroll
    for (int j = 0; j < L_; ++j) {
        float zz = (tile[j][c] - mu_s[j]) * rs_s[j] * gw + gb;
        zz *= b2f(sr[base + (size_t)j * C_]);
        z[base + (size_t)j * C_] = f2b(zz);
    }
}

extern "C" void kernel_launch(void* const* d_in, const int* in_sizes, int n_in,
                              void* d_out, int out_size, void* d_ws, size_t ws_size,
                              hipStream_t stream) {
    const float* x     = (const float*)d_in[0];
    const float* Wk    = (const float*)d_in[1];
    const float* Wv    = (const float*)d_in[2];
    const float* Wr    = (const float*)d_in[3];
    const float* Wo    = (const float*)d_in[4];
    const float* decay = (const float*)d_in[5];
    const float* first = (const float*)d_in[6];
    const float* lnw   = (const float*)d_in[7];
    const float* lnb   = (const float*)d_in[8];
    float* out = (float*)d_out;

    char* ws = (char*)d_ws;
    const size_t NE = (size_t)M_ * C_;              // 8388608
    unsigned short* wb  = (unsigned short*)ws; ws += 4 * 65536 * 2;  // wk|wv|wr|wo
    unsigned short* xb  = (unsigned short*)ws; ws += NE * 2;
    float* kbuf = (float*)ws; ws += NE * 4;
    float* vbuf = (float*)ws; ws += NE * 4;
    unsigned short* srb = (unsigned short*)ws; ws += NE * 2;
    unsigned short* zb  = (unsigned short*)ws; ws += NE * 2;
    const size_t SE = (size_t)B_ * NC_ * C_;        // 524288
    float* sp = (float*)ws; ws += SE * 4;
    float* sq = (float*)ws; ws += SE * 4;
    float* so = (float*)ws; ws += SE * 4;
    unsigned short* wkb = wb;
    unsigned short* wvb = wb + 65536;
    unsigned short* wrb = wb + 2 * 65536;
    unsigned short* wob = wb + 3 * 65536;

    cvt_all<<<4096 + 128, 256, 0, stream>>>(x, Wk, Wv, Wr, Wo, xb, wb);

    // QKV: 256 row-blocks x 4 col-strips x 3 mats = 3072 blocks
    gemm_wlds<<<dim3(M_ / 128, 4, 3), 256, 0, stream>>>(xb, wkb, wvb, wrb,
                                                        kbuf, vbuf, srb);

    wkv_pass1<<<dim3(NC_, B_), 256, 0, stream>>>(kbuf, vbuf, decay, sp, sq, so);
    wkv_combine<<<B_, 256, 0, stream>>>(decay, sp, sq, so);
    wkv_pass2_ln<<<dim3(NC_, B_), 256, 0, stream>>>(kbuf, vbuf, srb, decay, first,
                                                    lnw, lnb, sp, sq, so, zb);

    // Output GEMM: 256 row-blocks x 4 col-strips = 1024 blocks
    gemm_wlds<<<dim3(M_ / 128, 4, 1), 256, 0, stream>>>(zb, wob, wob, wob,
                                                        out, nullptr, nullptr);
}